// Round 9
// baseline (280.559 us; speedup 1.0000x reference)
//
#include <hip/hip_runtime.h>
#include <math.h>

#define N_NODES 20000
#define N_EDGES 320000
#define NODE_DIM 256
#define HID 64
#define HEADS 4
#define OUTC 50
#define NEG_SLOPE 0.2f
#define BN_EPS 1e-5f
#define LOG2E 1.4426950408889634f

typedef __attribute__((ext_vector_type(8))) short short8;
typedef __attribute__((ext_vector_type(8))) unsigned short ushort8;
typedef __attribute__((ext_vector_type(4))) unsigned short ushort4v;
typedef __attribute__((ext_vector_type(4))) float f32x4;

__device__ inline unsigned short f2bf(float f) {
  unsigned u = __float_as_uint(f);
  u += 0x7fffu + ((u >> 16) & 1u);
  return (unsigned short)(u >> 16);
}

__device__ inline float bf2f(unsigned short u) {
  return __uint_as_float((unsigned)u << 16);
}

__device__ inline float gelu_exact(float v) {
  return 0.5f * v * (1.f + erff(v * 0.70710678118f));
}

// ---------------- fused casts: x -> bf16, weights -> concat bf16 ----------------
__global__ void cast_all_kernel(const float* __restrict__ x, unsigned short* __restrict__ xb,
                                const float* __restrict__ W1l, const float* __restrict__ W1r,
                                const float* __restrict__ W2l, const float* __restrict__ W2r,
                                unsigned short* __restrict__ w1b,
                                unsigned short* __restrict__ w2b) {
  int i = blockIdx.x * blockDim.x + threadIdx.x;
  if (i < 1280000) {
    float4 v = ((const float4*)x)[i];
    ushort4v o = {f2bf(v.x), f2bf(v.y), f2bf(v.z), f2bf(v.w)};
    ((ushort4v*)xb)[i] = o;
  }
  if (i < 131072) {
    int k = i >> 9, j = i & 511;
    w1b[i] = f2bf(j < 256 ? W1l[k * 256 + j] : W1r[k * 256 + j - 256]);
  }
  if (i < 32768) {
    int k = i >> 7, j = i & 127;
    w2b[i] = f2bf(j < 64 ? W2l[k * 64 + j] : W2r[k * 64 + j - 64]);
  }
}

// ---------------- bf16 MFMA GEMM: C[M,N] = A[M,K] @ B[K,N], bf16 out ----------------
// BM=128, BN=128, BK=32. 256 threads = 4 waves.
__global__ __launch_bounds__(256) void gemm_bf16_kernel(
    const unsigned short* __restrict__ A, const unsigned short* __restrict__ B,
    unsigned short* __restrict__ C, int M, int K, int N) {
  __shared__ unsigned short As[128][40];
  __shared__ unsigned short Bs[128][40];
  int tid = threadIdx.x;
  int lane = tid & 63, w = tid >> 6;
  int bm = blockIdx.y * 128, bn = blockIdx.x * 128;

  f32x4 acc[2][8] = {};

  for (int k0 = 0; k0 < K; k0 += 32) {
#pragma unroll
    for (int s = tid; s < 512; s += 256) {
      int row = s >> 2, half = s & 3;
      int gr = bm + row;
      ushort8 v = {0, 0, 0, 0, 0, 0, 0, 0};
      if (gr < M) v = *(const ushort8*)&A[(size_t)gr * K + k0 + half * 8];
      *(ushort8*)&As[row][half * 8] = v;
    }
#pragma unroll
    for (int s = tid; s < 512; s += 256) {
      int k = s >> 4, c0 = (s & 15) * 8;
      ushort8 v = *(const ushort8*)&B[(size_t)(k0 + k) * N + bn + c0];
#pragma unroll
      for (int j = 0; j < 8; j++) Bs[c0 + j][k] = v[j];
    }
    __syncthreads();

    short8 av[2], bv[8];
#pragma unroll
    for (int fr = 0; fr < 2; fr++)
      av[fr] = *(const short8*)&As[w * 32 + fr * 16 + (lane & 15)][(lane >> 4) * 8];
#pragma unroll
    for (int fc = 0; fc < 8; fc++)
      bv[fc] = *(const short8*)&Bs[fc * 16 + (lane & 15)][(lane >> 4) * 8];
#pragma unroll
    for (int fr = 0; fr < 2; fr++)
#pragma unroll
      for (int fc = 0; fc < 8; fc++)
        acc[fr][fc] = __builtin_amdgcn_mfma_f32_16x16x32_bf16(av[fr], bv[fc], acc[fr][fc], 0, 0, 0);
    __syncthreads();
  }

#pragma unroll
  for (int fr = 0; fr < 2; fr++)
#pragma unroll
    for (int fc = 0; fc < 8; fc++)
#pragma unroll
      for (int i = 0; i < 4; i++) {
        int r = bm + w * 32 + fr * 16 + (lane >> 4) * 4 + i;
        if (r < M) C[(size_t)r * N + bn + fc * 16 + (lane & 15)] = f2bf(acc[fr][fc][i]);
      }
}

// ---------------- GEMM2 with fused BN1+GELU+cast on the A operand ----------------
// A32 = out1 f32 [M][256]; applies a = gelu(v*ss[c]+ss[256+c]) while staging bf16.
__global__ __launch_bounds__(256) void gemm2_fused_kernel(
    const float* __restrict__ A32, const float* __restrict__ ss,
    const unsigned short* __restrict__ B, unsigned short* __restrict__ C,
    int M, int K, int N) {
  __shared__ unsigned short As[128][40];
  __shared__ unsigned short Bs[128][40];
  __shared__ float ssA[512];
  int tid = threadIdx.x;
  int lane = tid & 63, w = tid >> 6;
  int bm = blockIdx.y * 128, bn = blockIdx.x * 128;

  for (int i = tid; i < 512; i += 256) ssA[i] = ss[i];
  __syncthreads();

  f32x4 acc[2][8] = {};

  for (int k0 = 0; k0 < K; k0 += 32) {
#pragma unroll
    for (int s = tid; s < 512; s += 256) {
      int row = s >> 2, half = s & 3;
      int gr = bm + row;
      int c0 = k0 + half * 8;
      ushort8 o8 = {0, 0, 0, 0, 0, 0, 0, 0};
      if (gr < M) {
        float4 va = *(const float4*)&A32[(size_t)gr * K + c0];
        float4 vb = *(const float4*)&A32[(size_t)gr * K + c0 + 4];
        o8[0] = f2bf(gelu_exact(va.x * ssA[c0 + 0] + ssA[256 + c0 + 0]));
        o8[1] = f2bf(gelu_exact(va.y * ssA[c0 + 1] + ssA[256 + c0 + 1]));
        o8[2] = f2bf(gelu_exact(va.z * ssA[c0 + 2] + ssA[256 + c0 + 2]));
        o8[3] = f2bf(gelu_exact(va.w * ssA[c0 + 3] + ssA[256 + c0 + 3]));
        o8[4] = f2bf(gelu_exact(vb.x * ssA[c0 + 4] + ssA[256 + c0 + 4]));
        o8[5] = f2bf(gelu_exact(vb.y * ssA[c0 + 5] + ssA[256 + c0 + 5]));
        o8[6] = f2bf(gelu_exact(vb.z * ssA[c0 + 6] + ssA[256 + c0 + 6]));
        o8[7] = f2bf(gelu_exact(vb.w * ssA[c0 + 7] + ssA[256 + c0 + 7]));
      }
      *(ushort8*)&As[row][half * 8] = o8;
    }
#pragma unroll
    for (int s = tid; s < 512; s += 256) {
      int k = s >> 4, c0 = (s & 15) * 8;
      ushort8 v = *(const ushort8*)&B[(size_t)(k0 + k) * N + bn + c0];
#pragma unroll
      for (int j = 0; j < 8; j++) Bs[c0 + j][k] = v[j];
    }
    __syncthreads();

    short8 av[2], bv[8];
#pragma unroll
    for (int fr = 0; fr < 2; fr++)
      av[fr] = *(const short8*)&As[w * 32 + fr * 16 + (lane & 15)][(lane >> 4) * 8];
#pragma unroll
    for (int fc = 0; fc < 8; fc++)
      bv[fc] = *(const short8*)&Bs[fc * 16 + (lane & 15)][(lane >> 4) * 8];
#pragma unroll
    for (int fr = 0; fr < 2; fr++)
#pragma unroll
      for (int fc = 0; fc < 8; fc++)
        acc[fr][fc] = __builtin_amdgcn_mfma_f32_16x16x32_bf16(av[fr], bv[fc], acc[fr][fc], 0, 0, 0);
    __syncthreads();
  }

#pragma unroll
  for (int fr = 0; fr < 2; fr++)
#pragma unroll
    for (int fc = 0; fc < 8; fc++)
#pragma unroll
      for (int i = 0; i < 4; i++) {
        int r = bm + w * 32 + fr * 16 + (lane >> 4) * 4 + i;
        if (r < M) C[(size_t)r * N + bn + fc * 16 + (lane & 15)] = f2bf(acc[fr][fc][i]);
      }
}

// ---------------- CSR build ----------------
__global__ void hist_kernel(const int* __restrict__ dst, int* __restrict__ deg) {
  int i = blockIdx.x * blockDim.x + threadIdx.x;
  if (i < N_EDGES) atomicAdd(&deg[dst[i]], 1);
}

__global__ void scan_kernel(const int* __restrict__ deg, int* __restrict__ rowptr) {
  __shared__ int part[1024];
  int tid = threadIdx.x;
  const int CH = (N_NODES + 1023) / 1024;  // 20
  int base = tid * CH;
  int s = 0;
  for (int i = 0; i < CH; i++) {
    int idx = base + i;
    if (idx < N_NODES) s += deg[idx];
  }
  part[tid] = s;
  __syncthreads();
  for (int off = 1; off < 1024; off <<= 1) {
    int v = (tid >= off) ? part[tid - off] : 0;
    __syncthreads();
    part[tid] += v;
    __syncthreads();
  }
  int run = (tid == 0) ? 0 : part[tid - 1];
  for (int i = 0; i < CH; i++) {
    int idx = base + i;
    if (idx < N_NODES) {
      rowptr[idx] = run;
      run += deg[idx];
    }
  }
  if (tid == 1023) rowptr[N_NODES] = run;
}

__global__ void scatter_kernel(const int* __restrict__ src, const int* __restrict__ dst,
                               const int* __restrict__ rowptr, int* __restrict__ cursor,
                               int* __restrict__ csr_src) {
  int i = blockIdx.x * blockDim.x + threadIdx.x;
  if (i < N_EDGES) {
    int d = dst[i];
    int pos = rowptr[d] + atomicAdd(&cursor[d], 1);
    csr_src[pos] = src[i];
  }
}

// ---------------- GATv2 aggregation, layer 1 (software-pipelined) ----------------
// Wave per node. Lane l: head h=l>>4, channels 4l..4l+3. 4-step group butterfly.
// Prefetch next 4 edge rows while computing current 4.
__global__ void agg1_kernel(const unsigned short* __restrict__ C1,
                            const float* __restrict__ att, const float* __restrict__ bias,
                            const int* __restrict__ rowptr, const int* __restrict__ csr_src,
                            float* __restrict__ out) {
  int wave = threadIdx.x >> 6;
  int lane = threadIdx.x & 63;
  int n = blockIdx.x * 4 + wave;
  if (n >= N_NODES) return;

  const size_t L4 = 4 * (size_t)lane;
  ushort4v xi4 = *(const ushort4v*)&C1[(size_t)n * 512 + 256 + L4];
  float xi0 = bf2f(xi4[0]), xi1 = bf2f(xi4[1]), xi2 = bf2f(xi4[2]), xi3 = bf2f(xi4[3]);
  float4 attv = *(const float4*)&att[4 * lane];
  attv.x *= LOG2E; attv.y *= LOG2E; attv.z *= LOG2E; attv.w *= LOG2E;

  float acc0 = 0.f, acc1 = 0.f, acc2 = 0.f, acc3 = 0.f;
  float lsum = 0.f;

  int e0 = rowptr[n], e1 = rowptr[n + 1];
  int nb = e1 - e0;

  if (nb > 0) {
    int ng = (nb + 3) >> 2;
    // prefetch group 0
    int ia = e0;
    int ib = min(e0 + 1, e1 - 1);
    int ic = min(e0 + 2, e1 - 1);
    int id = min(e0 + 3, e1 - 1);
    ushort4v A4 = *(const ushort4v*)&C1[(size_t)csr_src[ia] * 512 + L4];
    ushort4v B4 = *(const ushort4v*)&C1[(size_t)csr_src[ib] * 512 + L4];
    ushort4v C4 = *(const ushort4v*)&C1[(size_t)csr_src[ic] * 512 + L4];
    ushort4v D4 = *(const ushort4v*)&C1[(size_t)csr_src[id] * 512 + L4];

    for (int it = 0; it < ng; it++) {
      int base = e0 + it * 4;
      bool v1 = base + 1 < e1, v2 = base + 2 < e1, v3 = base + 3 < e1;

      ushort4v ca = A4, cb = B4, cc = C4, cd = D4;

      // prefetch next group
      int nbase = base + 4;
      if (nbase < e1) {
        int na = nbase;
        int nb2 = min(nbase + 1, e1 - 1);
        int nc = min(nbase + 2, e1 - 1);
        int nd = min(nbase + 3, e1 - 1);
        A4 = *(const ushort4v*)&C1[(size_t)csr_src[na] * 512 + L4];
        B4 = *(const ushort4v*)&C1[(size_t)csr_src[nb2] * 512 + L4];
        C4 = *(const ushort4v*)&C1[(size_t)csr_src[nc] * 512 + L4];
        D4 = *(const ushort4v*)&C1[(size_t)csr_src[nd] * 512 + L4];
      }

      float xa0 = bf2f(ca[0]), xa1 = bf2f(ca[1]), xa2 = bf2f(ca[2]), xa3 = bf2f(ca[3]);
      float xb0 = bf2f(cb[0]), xb1 = bf2f(cb[1]), xb2 = bf2f(cb[2]), xb3 = bf2f(cb[3]);
      float xc0 = bf2f(cc[0]), xc1 = bf2f(cc[1]), xc2 = bf2f(cc[2]), xc3 = bf2f(cc[3]);
      float xd0 = bf2f(cd[0]), xd1 = bf2f(cd[1]), xd2 = bf2f(cd[2]), xd3 = bf2f(cd[3]);

      float ua0 = xi0 + xa0, ua1 = xi1 + xa1, ua2 = xi2 + xa2, ua3 = xi3 + xa3;
      float ub0 = xi0 + xb0, ub1 = xi1 + xb1, ub2 = xi2 + xb2, ub3 = xi3 + xb3;
      float uc0 = xi0 + xc0, uc1 = xi1 + xc1, uc2 = xi2 + xc2, uc3 = xi3 + xc3;
      float ud0 = xi0 + xd0, ud1 = xi1 + xd1, ud2 = xi2 + xd2, ud3 = xi3 + xd3;

      float ta = fmaxf(ua0, NEG_SLOPE * ua0) * attv.x + fmaxf(ua1, NEG_SLOPE * ua1) * attv.y +
                 fmaxf(ua2, NEG_SLOPE * ua2) * attv.z + fmaxf(ua3, NEG_SLOPE * ua3) * attv.w;
      float tb = fmaxf(ub0, NEG_SLOPE * ub0) * attv.x + fmaxf(ub1, NEG_SLOPE * ub1) * attv.y +
                 fmaxf(ub2, NEG_SLOPE * ub2) * attv.z + fmaxf(ub3, NEG_SLOPE * ub3) * attv.w;
      float tc = fmaxf(uc0, NEG_SLOPE * uc0) * attv.x + fmaxf(uc1, NEG_SLOPE * uc1) * attv.y +
                 fmaxf(uc2, NEG_SLOPE * uc2) * attv.z + fmaxf(uc3, NEG_SLOPE * uc3) * attv.w;
      float td = fmaxf(ud0, NEG_SLOPE * ud0) * attv.x + fmaxf(ud1, NEG_SLOPE * ud1) * attv.y +
                 fmaxf(ud2, NEG_SLOPE * ud2) * attv.z + fmaxf(ud3, NEG_SLOPE * ud3) * attv.w;

      ta += __shfl_xor(ta, 8); tb += __shfl_xor(tb, 8); tc += __shfl_xor(tc, 8); td += __shfl_xor(td, 8);
      ta += __shfl_xor(ta, 4); tb += __shfl_xor(tb, 4); tc += __shfl_xor(tc, 4); td += __shfl_xor(td, 4);
      ta += __shfl_xor(ta, 2); tb += __shfl_xor(tb, 2); tc += __shfl_xor(tc, 2); td += __shfl_xor(td, 2);
      ta += __shfl_xor(ta, 1); tb += __shfl_xor(tb, 1); tc += __shfl_xor(tc, 1); td += __shfl_xor(td, 1);

      float pa = __builtin_amdgcn_exp2f(ta);
      float pb = v1 ? __builtin_amdgcn_exp2f(tb) : 0.f;
      float pc = v2 ? __builtin_amdgcn_exp2f(tc) : 0.f;
      float pd = v3 ? __builtin_amdgcn_exp2f(td) : 0.f;
      lsum += (pa + pb) + (pc + pd);
      acc0 += pa * xa0 + pb * xb0 + pc * xc0 + pd * xd0;
      acc1 += pa * xa1 + pb * xb1 + pc * xc1 + pd * xd1;
      acc2 += pa * xa2 + pb * xb2 + pc * xc2 + pd * xd2;
      acc3 += pa * xa3 + pb * xb3 + pc * xc3 + pd * xd3;
    }
  }

  float inv = 1.f / (lsum + 1e-16f);
  float4 bv = *(const float4*)&bias[4 * lane];
  float4 o;
  o.x = acc0 * inv + bv.x;
  o.y = acc1 * inv + bv.y;
  o.z = acc2 * inv + bv.z;
  o.w = acc3 * inv + bv.w;
  *(float4*)&out[(size_t)n * 256 + 4 * lane] = o;
}

// ---------------- GATv2 aggregation, layer 2 (prefetched) ----------------
// Wave per node; 4 x 16-lane groups each process a different edge (4 dims/lane).
__global__ void agg2_kernel(const unsigned short* __restrict__ xlr,
                            const float* __restrict__ att, const float* __restrict__ bias,
                            const int* __restrict__ rowptr, const int* __restrict__ csr_src,
                            float* __restrict__ out) {
  int wave = threadIdx.x >> 6;
  int lane = threadIdx.x & 63;
  int n = blockIdx.x * 4 + wave;
  if (n >= N_NODES) return;

  int g = lane >> 4, slot = lane & 15;
  ushort4v xi4 = *(const ushort4v*)&xlr[(size_t)n * 128 + 64 + 4 * slot];
  float xi0 = bf2f(xi4[0]), xi1 = bf2f(xi4[1]), xi2 = bf2f(xi4[2]), xi3 = bf2f(xi4[3]);
  float4 attv = *(const float4*)&att[4 * slot];
  attv.x *= LOG2E; attv.y *= LOG2E; attv.z *= LOG2E; attv.w *= LOG2E;

  float acc0 = 0.f, acc1 = 0.f, acc2 = 0.f, acc3 = 0.f;
  float lsum = 0.f;

  int e0 = rowptr[n], e1 = rowptr[n + 1];
  int nb = e1 - e0;
  if (nb > 0) {
    int nt = (nb + 3) >> 2;
    int ecl = min(e0 + g, e1 - 1);
    ushort4v R = *(const ushort4v*)&xlr[(size_t)csr_src[ecl] * 128 + 4 * slot];
    for (int it = 0; it < nt; it++) {
      bool valid = (e0 + it * 4 + g) < e1;
      ushort4v cur = R;
      if (it + 1 < nt) {
        int ne = min(e0 + (it + 1) * 4 + g, e1 - 1);
        R = *(const ushort4v*)&xlr[(size_t)csr_src[ne] * 128 + 4 * slot];
      }
      float xj0 = bf2f(cur[0]), xj1 = bf2f(cur[1]), xj2 = bf2f(cur[2]), xj3 = bf2f(cur[3]);
      float u0 = xi0 + xj0, u1 = xi1 + xj1, u2 = xi2 + xj2, u3 = xi3 + xj3;
      float t = fmaxf(u0, NEG_SLOPE * u0) * attv.x + fmaxf(u1, NEG_SLOPE * u1) * attv.y +
                fmaxf(u2, NEG_SLOPE * u2) * attv.z + fmaxf(u3, NEG_SLOPE * u3) * attv.w;
      t += __shfl_xor(t, 8);
      t += __shfl_xor(t, 4);
      t += __shfl_xor(t, 2);
      t += __shfl_xor(t, 1);
      float p = valid ? __builtin_amdgcn_exp2f(t) : 0.f;
      lsum += p;
      acc0 += p * xj0;
      acc1 += p * xj1;
      acc2 += p * xj2;
      acc3 += p * xj3;
    }
  }

  acc0 += __shfl_xor(acc0, 16); acc0 += __shfl_xor(acc0, 32);
  acc1 += __shfl_xor(acc1, 16); acc1 += __shfl_xor(acc1, 32);
  acc2 += __shfl_xor(acc2, 16); acc2 += __shfl_xor(acc2, 32);
  acc3 += __shfl_xor(acc3, 16); acc3 += __shfl_xor(acc3, 32);
  lsum += __shfl_xor(lsum, 16); lsum += __shfl_xor(lsum, 32);

  if (g == 0) {
    float inv = 1.f / (lsum + 1e-16f);
    float4 bv = *(const float4*)&bias[4 * slot];
    float4 o;
    o.x = acc0 * inv + bv.x;
    o.y = acc1 * inv + bv.y;
    o.z = acc2 * inv + bv.z;
    o.w = acc3 * inv + bv.w;
    *(float4*)&out[(size_t)n * 64 + 4 * slot] = o;
  }
}

// ---------------- BN stage 1, C=256 ----------------
__global__ void bn_stage1_256_kernel(const float* __restrict__ x, float* __restrict__ partial) {
  int c = threadIdx.x;
  int r0 = blockIdx.x * 84;
  int r1 = min(r0 + 84, N_NODES);
  float s = 0.f, q = 0.f;
  for (int r = r0; r < r1; r++) {
    float v = x[(size_t)r * 256 + c];
    s += v;
    q += v * v;
  }
  partial[(size_t)blockIdx.x * 512 + c] = s;
  partial[(size_t)blockIdx.x * 512 + 256 + c] = q;
}

// ---------------- BN stage 1, C=64 ----------------
__global__ void bn_stage1_64_kernel(const float* __restrict__ x, float* __restrict__ partial) {
  __shared__ float ls[256], lq[256];
  int tid = threadIdx.x;
  int c = tid & 63, g = tid >> 6;
  int r0 = blockIdx.x * 84 + g;
  int r1 = min(blockIdx.x * 84 + 84, N_NODES);
  float s = 0.f, q = 0.f;
  for (int r = r0; r < r1; r += 4) {
    float v = x[(size_t)r * 64 + c];
    s += v;
    q += v * v;
  }
  ls[tid] = s;
  lq[tid] = q;
  __syncthreads();
  if (g == 0) {
    s += ls[64 + c] + ls[128 + c] + ls[192 + c];
    q += lq[64 + c] + lq[128 + c] + lq[192 + c];
    partial[(size_t)blockIdx.x * 128 + c] = s;
    partial[(size_t)blockIdx.x * 128 + 64 + c] = q;
  }
}

// ---------------- BN stage 2: finalize scale/shift ----------------
__global__ void bn_stage2_kernel(const float* __restrict__ partial, int C,
                                 const float* __restrict__ gamma, const float* __restrict__ beta,
                                 float* __restrict__ ss) {
  int c = threadIdx.x;
  if (c >= C) return;
  float s = 0.f, q = 0.f;
  for (int b = 0; b < 240; b++) {
    s += partial[(size_t)b * 2 * C + c];
    q += partial[(size_t)b * 2 * C + C + c];
  }
  float mu = s * (1.0f / N_NODES);
  float var = q * (1.0f / N_NODES) - mu * mu;
  float sc = gamma[c] * rsqrtf(var + BN_EPS);
  ss[c] = sc;
  ss[C + c] = beta[c] - mu * sc;
}

// ---------------- classifier head: fused BN2+GELU on load, + log_softmax ----------------
__global__ void head_kernel(const float* __restrict__ h, const float* __restrict__ ss2,
                            const float* __restrict__ Wc, const float* __restrict__ bc,
                            float* __restrict__ out) {
  __shared__ float Ws[HID * OUTC];
  __shared__ float bs[OUTC];
  for (int i = threadIdx.x; i < HID * OUTC; i += 256) Ws[i] = Wc[i];
  for (int i = threadIdx.x; i < OUTC; i += 256) bs[i] = bc[i];
  __syncthreads();

  int wave = threadIdx.x >> 6;
  int lane = threadIdx.x & 63;
  int n = blockIdx.x * 4 + wave;
  if (n >= N_NODES) return;

  float raw = h[(size_t)n * HID + lane];
  float hrow = gelu_exact(raw * ss2[lane] + ss2[64 + lane]);
  float dot = 0.f;
#pragma unroll
  for (int k = 0; k < HID; k++) {
    float hk = __shfl(hrow, k);
    if (lane < OUTC) dot += hk * Ws[k * OUTC + lane];
  }
  float z = (lane < OUTC) ? (dot + bs[lane]) : -INFINITY;
  float mv = z;
  for (int off = 32; off; off >>= 1) mv = fmaxf(mv, __shfl_xor(mv, off));
  float p = (lane < OUTC) ? expf(z - mv) : 0.f;
  float sum = p;
  for (int off = 32; off; off >>= 1) sum += __shfl_xor(sum, off);
  if (lane < OUTC) out[(size_t)n * OUTC + lane] = z - mv - logf(sum);
}

// ---------------- launch ----------------
extern "C" void kernel_launch(void* const* d_in, const int* in_sizes, int n_in,
                              void* d_out, int out_size, void* d_ws, size_t ws_size,
                              hipStream_t stream) {
  const float* x = (const float*)d_in[0];
  const int* eidx = (const int*)d_in[1];
  const float* W1l = (const float*)d_in[2];
  const float* W1r = (const float*)d_in[3];
  const float* att1 = (const float*)d_in[4];
  const float* b1 = (const float*)d_in[5];
  const float* bn1_g = (const float*)d_in[6];
  const float* bn1_b = (const float*)d_in[7];
  const float* W2l = (const float*)d_in[8];
  const float* W2r = (const float*)d_in[9];
  const float* att2 = (const float*)d_in[10];
  const float* b2 = (const float*)d_in[11];
  const float* bn2_g = (const float*)d_in[12];
  const float* bn2_b = (const float*)d_in[13];
  const float* Wc = (const float*)d_in[14];
  const float* bc = (const float*)d_in[15];
  float* out = (float*)d_out;

  const int* src = eidx;
  const int* dstv = eidx + N_EDGES;

  char* ws = (char*)d_ws;
  unsigned short* C1full = (unsigned short*)(ws + 0);        // [20000][512] bf16, 20,480,000
  float* out1 = (float*)(ws + 20971520);                     // [20000][256] f32, 20,480,000
  unsigned short* C2full = (unsigned short*)(ws + 52428800); // [20000][128] bf16, 5,120,000
  unsigned short* xb = (unsigned short*)(ws + 62914560);     // [20000][256] bf16, 10,240,000
  float* out2 = (float*)(ws + 62914560);                     // 5,120,000 (after xb dead)
  float* partial = (float*)(ws + 73400320);                  // 240*512 f32 = 491,520
  float* ss1 = (float*)(ws + 73891840);                      // 512 f32
  float* ss2 = (float*)(ws + 73893888);                      // 128 f32
  unsigned short* w1b = (unsigned short*)(ws + 73894400);    // 262,144
  unsigned short* w2b = (unsigned short*)(ws + 74156544);    // 65,536
  int* deg = (int*)(ws + 74222080);                          // 80,000
  int* cursor = (int*)(ws + 74302080);                       // 80,000 (contiguous)
  int* rowptr = (int*)(ws + 74382080);                       // 80,016
  int* csr_src = (int*)(ws + 74462096);                      // 1,280,000 -> ends 75,742,096

  hipMemsetAsync(deg, 0, 160000, stream);  // deg + cursor

  // fused casts
  cast_all_kernel<<<5000, 256, 0, stream>>>(x, xb, W1l, W1r, W2l, W2r, w1b, w2b);

  // layer-1 transform: one GEMM, N=512 ([xl | xr]), bf16 out
  gemm_bf16_kernel<<<dim3(4, 157), 256, 0, stream>>>(xb, w1b, C1full, N_NODES, 256, 512);

  // CSR build
  hist_kernel<<<(N_EDGES + 255) / 256, 256, 0, stream>>>(dstv, deg);
  scan_kernel<<<1, 1024, 0, stream>>>(deg, rowptr);
  scatter_kernel<<<(N_EDGES + 255) / 256, 256, 0, stream>>>(src, dstv, rowptr, cursor, csr_src);

  // layer-1 attention aggregation (+bias) -> out1 (f32)
  agg1_kernel<<<N_NODES / 4, 256, 0, stream>>>(C1full, att1, b1, rowptr, csr_src, out1);

  // BN1 stats (finalize+GELU fused into GEMM2's A staging)
  bn_stage1_256_kernel<<<240, 256, 0, stream>>>(out1, partial);
  bn_stage2_kernel<<<1, 256, 0, stream>>>(partial, 256, bn1_g, bn1_b, ss1);

  // layer-2 transform: fused BN1+GELU+cast + GEMM, N=128 ([xl2 | xr2]), bf16 out
  gemm2_fused_kernel<<<dim3(1, 157), 256, 0, stream>>>(out1, ss1, w2b, C2full, N_NODES, 256, 128);

  // layer-2 attention aggregation (+bias)
  agg2_kernel<<<N_NODES / 4, 256, 0, stream>>>(C2full, att2, b2, rowptr, csr_src, out2);

  // BN2 stats (finalize+GELU fused into head)
  bn_stage1_64_kernel<<<240, 256, 0, stream>>>(out2, partial);
  bn_stage2_kernel<<<1, 64, 0, stream>>>(partial, 64, bn2_g, bn2_b, ss2);

  // classifier + log_softmax (BN2+GELU applied on load)
  head_kernel<<<N_NODES / 4, 256, 0, stream>>>(out2, ss2, Wc, bc, out);
}

// Round 10
// 263.714 us; speedup vs baseline: 1.0639x; 1.0639x over previous
//
#include <hip/hip_runtime.h>
#include <math.h>

#define N_NODES 20000
#define N_EDGES 320000
#define NODE_DIM 256
#define HID 64
#define HEADS 4
#define OUTC 50
#define NEG_SLOPE 0.2f
#define BN_EPS 1e-5f
#define LOG2E 1.4426950408889634f

typedef __attribute__((ext_vector_type(8))) short short8;
typedef __attribute__((ext_vector_type(8))) unsigned short ushort8;
typedef __attribute__((ext_vector_type(4))) unsigned short ushort4v;
typedef __attribute__((ext_vector_type(4))) float f32x4;

__device__ inline unsigned short f2bf(float f) {
  unsigned u = __float_as_uint(f);
  u += 0x7fffu + ((u >> 16) & 1u);
  return (unsigned short)(u >> 16);
}

__device__ inline float bf2f(unsigned short u) {
  return __uint_as_float((unsigned)u << 16);
}

__device__ inline float gelu_exact(float v) {
  return 0.5f * v * (1.f + erff(v * 0.70710678118f));
}

// ---------------- fused: x cast, weight transpose-cast, degree histogram ----------------
// w1bT[512][256] = [W1l | W1r]^T, w2bT[128][256] = [W2l | W2r]^T
__global__ void cast_all_kernel(const float* __restrict__ x, unsigned short* __restrict__ xb,
                                const float* __restrict__ W1l, const float* __restrict__ W1r,
                                const float* __restrict__ W2l, const float* __restrict__ W2r,
                                unsigned short* __restrict__ w1bT,
                                unsigned short* __restrict__ w2bT,
                                const int* __restrict__ dst, int* __restrict__ deg) {
  int i = blockIdx.x * blockDim.x + threadIdx.x;
  if (i < 1280000) {
    float4 v = ((const float4*)x)[i];
    ushort4v o = {f2bf(v.x), f2bf(v.y), f2bf(v.z), f2bf(v.w)};
    ((ushort4v*)xb)[i] = o;
  }
  if (i < 131072) {
    int j = i >> 8, k = i & 255;  // j = output col, k = input dim
    w1bT[i] = f2bf(j < 256 ? W1l[k * 256 + j] : W1r[k * 256 + j - 256]);
  }
  if (i < 32768) {
    int j = i >> 8, k = i & 255;
    w2bT[i] = f2bf(j < 64 ? W2l[k * 64 + j] : W2r[k * 64 + j - 64]);
  }
  if (i < N_EDGES) atomicAdd(&deg[dst[i]], 1);
}

// ---------------- bf16 MFMA GEMM: C[M,N] = A[M,K] @ BT[N,K]^T, bf16 out ----------------
// BM=128, BN=128, BK=32. 256 threads = 4 waves. Extra grid row (y==gridDim.y-1,x==0)
// runs the 256-thread exclusive scan of deg -> rowptr (fused to save a dispatch).
__global__ __launch_bounds__(256) void gemm_bf16_kernel(
    const unsigned short* __restrict__ A, const unsigned short* __restrict__ BT,
    unsigned short* __restrict__ C, int M, int K, int N,
    const int* __restrict__ deg, int* __restrict__ rowptr) {
  if (blockIdx.y == gridDim.y - 1) {
    if (blockIdx.x == 0) {
      __shared__ int part[256];
      int tid = threadIdx.x;
      const int CH = 79;  // ceil(20000/256)
      int base = tid * CH;
      int s = 0;
      for (int i = 0; i < CH; i++) {
        int idx = base + i;
        if (idx < N_NODES) s += deg[idx];
      }
      part[tid] = s;
      __syncthreads();
      for (int off = 1; off < 256; off <<= 1) {
        int v = (tid >= off) ? part[tid - off] : 0;
        __syncthreads();
        part[tid] += v;
        __syncthreads();
      }
      int run = (tid == 0) ? 0 : part[tid - 1];
      for (int i = 0; i < CH; i++) {
        int idx = base + i;
        if (idx < N_NODES) {
          rowptr[idx] = run;
          run += deg[idx];
        }
      }
      if (tid == 255) rowptr[N_NODES] = run;
    }
    return;
  }

  __shared__ unsigned short As[128][40];
  __shared__ unsigned short Bs[128][40];
  int tid = threadIdx.x;
  int lane = tid & 63, w = tid >> 6;
  int bm = blockIdx.y * 128, bn = blockIdx.x * 128;

  f32x4 acc[2][8] = {};

  for (int k0 = 0; k0 < K; k0 += 32) {
#pragma unroll
    for (int s = tid; s < 512; s += 256) {
      int row = s >> 2, half = s & 3;
      int gr = bm + row;
      ushort8 v = {0, 0, 0, 0, 0, 0, 0, 0};
      if (gr < M) v = *(const ushort8*)&A[(size_t)gr * K + k0 + half * 8];
      *(ushort8*)&As[row][half * 8] = v;
    }
#pragma unroll
    for (int s = tid; s < 512; s += 256) {
      int row = s >> 2, half = s & 3;
      ushort8 v = *(const ushort8*)&BT[(size_t)(bn + row) * K + k0 + half * 8];
      *(ushort8*)&Bs[row][half * 8] = v;
    }
    __syncthreads();

    short8 av[2], bv[8];
#pragma unroll
    for (int fr = 0; fr < 2; fr++)
      av[fr] = *(const short8*)&As[w * 32 + fr * 16 + (lane & 15)][(lane >> 4) * 8];
#pragma unroll
    for (int fc = 0; fc < 8; fc++)
      bv[fc] = *(const short8*)&Bs[fc * 16 + (lane & 15)][(lane >> 4) * 8];
#pragma unroll
    for (int fr = 0; fr < 2; fr++)
#pragma unroll
      for (int fc = 0; fc < 8; fc++)
        acc[fr][fc] = __builtin_amdgcn_mfma_f32_16x16x32_bf16(av[fr], bv[fc], acc[fr][fc], 0, 0, 0);
    __syncthreads();
  }

#pragma unroll
  for (int fr = 0; fr < 2; fr++)
#pragma unroll
    for (int fc = 0; fc < 8; fc++)
#pragma unroll
      for (int i = 0; i < 4; i++) {
        int r = bm + w * 32 + fr * 16 + (lane >> 4) * 4 + i;
        if (r < M) C[(size_t)r * N + bn + fc * 16 + (lane & 15)] = f2bf(acc[fr][fc][i]);
      }
}

// ---------------- GEMM2 with fused BN1+GELU+cast on the A operand ----------------
__global__ __launch_bounds__(256) void gemm2_fused_kernel(
    const float* __restrict__ A32, const float* __restrict__ ss,
    const unsigned short* __restrict__ BT, unsigned short* __restrict__ C,
    int M, int K, int N) {
  __shared__ unsigned short As[128][40];
  __shared__ unsigned short Bs[128][40];
  __shared__ float ssA[512];
  int tid = threadIdx.x;
  int lane = tid & 63, w = tid >> 6;
  int bm = blockIdx.y * 128, bn = blockIdx.x * 128;

  for (int i = tid; i < 512; i += 256) ssA[i] = ss[i];
  __syncthreads();

  f32x4 acc[2][8] = {};

  for (int k0 = 0; k0 < K; k0 += 32) {
#pragma unroll
    for (int s = tid; s < 512; s += 256) {
      int row = s >> 2, half = s & 3;
      int gr = bm + row;
      int c0 = k0 + half * 8;
      ushort8 o8 = {0, 0, 0, 0, 0, 0, 0, 0};
      if (gr < M) {
        float4 va = *(const float4*)&A32[(size_t)gr * K + c0];
        float4 vb = *(const float4*)&A32[(size_t)gr * K + c0 + 4];
        o8[0] = f2bf(gelu_exact(va.x * ssA[c0 + 0] + ssA[256 + c0 + 0]));
        o8[1] = f2bf(gelu_exact(va.y * ssA[c0 + 1] + ssA[256 + c0 + 1]));
        o8[2] = f2bf(gelu_exact(va.z * ssA[c0 + 2] + ssA[256 + c0 + 2]));
        o8[3] = f2bf(gelu_exact(va.w * ssA[c0 + 3] + ssA[256 + c0 + 3]));
        o8[4] = f2bf(gelu_exact(vb.x * ssA[c0 + 4] + ssA[256 + c0 + 4]));
        o8[5] = f2bf(gelu_exact(vb.y * ssA[c0 + 5] + ssA[256 + c0 + 5]));
        o8[6] = f2bf(gelu_exact(vb.z * ssA[c0 + 6] + ssA[256 + c0 + 6]));
        o8[7] = f2bf(gelu_exact(vb.w * ssA[c0 + 7] + ssA[256 + c0 + 7]));
      }
      *(ushort8*)&As[row][half * 8] = o8;
    }
#pragma unroll
    for (int s = tid; s < 512; s += 256) {
      int row = s >> 2, half = s & 3;
      ushort8 v = *(const ushort8*)&BT[(size_t)(bn + row) * K + k0 + half * 8];
      *(ushort8*)&Bs[row][half * 8] = v;
    }
    __syncthreads();

    short8 av[2], bv[8];
#pragma unroll
    for (int fr = 0; fr < 2; fr++)
      av[fr] = *(const short8*)&As[w * 32 + fr * 16 + (lane & 15)][(lane >> 4) * 8];
#pragma unroll
    for (int fc = 0; fc < 8; fc++)
      bv[fc] = *(const short8*)&Bs[fc * 16 + (lane & 15)][(lane >> 4) * 8];
#pragma unroll
    for (int fr = 0; fr < 2; fr++)
#pragma unroll
      for (int fc = 0; fc < 8; fc++)
        acc[fr][fc] = __builtin_amdgcn_mfma_f32_16x16x32_bf16(av[fr], bv[fc], acc[fr][fc], 0, 0, 0);
    __syncthreads();
  }

#pragma unroll
  for (int fr = 0; fr < 2; fr++)
#pragma unroll
    for (int fc = 0; fc < 8; fc++)
#pragma unroll
      for (int i = 0; i < 4; i++) {
        int r = bm + w * 32 + fr * 16 + (lane >> 4) * 4 + i;
        if (r < M) C[(size_t)r * N + bn + fc * 16 + (lane & 15)] = f2bf(acc[fr][fc][i]);
      }
}

// ---------------- CSR scatter ----------------
__global__ void scatter_kernel(const int* __restrict__ src, const int* __restrict__ dst,
                               const int* __restrict__ rowptr, int* __restrict__ cursor,
                               int* __restrict__ csr_src) {
  int i = blockIdx.x * blockDim.x + threadIdx.x;
  if (i < N_EDGES) {
    int d = dst[i];
    int pos = rowptr[d] + atomicAdd(&cursor[d], 1);
    csr_src[pos] = src[i];
  }
}

// ---------------- GATv2 aggregation, layer 1 ----------------
// Wave per node. Lane l: head h=l>>4, channels 4l..4l+3. 4-step group butterfly.
// att pre-scaled by LOG2E so p = exp2(t). Edge loop unrolled x4.
__global__ void agg1_kernel(const unsigned short* __restrict__ C1,
                            const float* __restrict__ att, const float* __restrict__ bias,
                            const int* __restrict__ rowptr, const int* __restrict__ csr_src,
                            float* __restrict__ out) {
  int wave = threadIdx.x >> 6;
  int lane = threadIdx.x & 63;
  int n = blockIdx.x * 4 + wave;
  if (n >= N_NODES) return;

  ushort4v xi4 = *(const ushort4v*)&C1[(size_t)n * 512 + 256 + 4 * lane];
  float xi0 = bf2f(xi4[0]), xi1 = bf2f(xi4[1]), xi2 = bf2f(xi4[2]), xi3 = bf2f(xi4[3]);
  float4 attv = *(const float4*)&att[4 * lane];
  attv.x *= LOG2E; attv.y *= LOG2E; attv.z *= LOG2E; attv.w *= LOG2E;

  float acc0 = 0.f, acc1 = 0.f, acc2 = 0.f, acc3 = 0.f;
  float lsum = 0.f;

  int e0 = rowptr[n], e1 = rowptr[n + 1];
  int e = e0;
#define EDGE_SCORE(T, X0, X1, X2, X3)                                                 \
  {                                                                                   \
    float u0 = xi0 + X0, u1 = xi1 + X1, u2 = xi2 + X2, u3 = xi3 + X3;                 \
    T = fmaxf(u0, NEG_SLOPE * u0) * attv.x + fmaxf(u1, NEG_SLOPE * u1) * attv.y +     \
        fmaxf(u2, NEG_SLOPE * u2) * attv.z + fmaxf(u3, NEG_SLOPE * u3) * attv.w;      \
  }
  for (; e + 4 <= e1; e += 4) {
    int s0 = csr_src[e], s1 = csr_src[e + 1], s2 = csr_src[e + 2], s3 = csr_src[e + 3];
    ushort4v a4 = *(const ushort4v*)&C1[(size_t)s0 * 512 + 4 * lane];
    ushort4v b4 = *(const ushort4v*)&C1[(size_t)s1 * 512 + 4 * lane];
    ushort4v c4 = *(const ushort4v*)&C1[(size_t)s2 * 512 + 4 * lane];
    ushort4v d4 = *(const ushort4v*)&C1[(size_t)s3 * 512 + 4 * lane];
    float xa0 = bf2f(a4[0]), xa1 = bf2f(a4[1]), xa2 = bf2f(a4[2]), xa3 = bf2f(a4[3]);
    float xb0 = bf2f(b4[0]), xb1 = bf2f(b4[1]), xb2 = bf2f(b4[2]), xb3 = bf2f(b4[3]);
    float xc0 = bf2f(c4[0]), xc1 = bf2f(c4[1]), xc2 = bf2f(c4[2]), xc3 = bf2f(c4[3]);
    float xd0 = bf2f(d4[0]), xd1 = bf2f(d4[1]), xd2 = bf2f(d4[2]), xd3 = bf2f(d4[3]);

    float ta, tb, tc, td;
    EDGE_SCORE(ta, xa0, xa1, xa2, xa3);
    EDGE_SCORE(tb, xb0, xb1, xb2, xb3);
    EDGE_SCORE(tc, xc0, xc1, xc2, xc3);
    EDGE_SCORE(td, xd0, xd1, xd2, xd3);

    ta += __shfl_xor(ta, 8); tb += __shfl_xor(tb, 8); tc += __shfl_xor(tc, 8); td += __shfl_xor(td, 8);
    ta += __shfl_xor(ta, 4); tb += __shfl_xor(tb, 4); tc += __shfl_xor(tc, 4); td += __shfl_xor(td, 4);
    ta += __shfl_xor(ta, 2); tb += __shfl_xor(tb, 2); tc += __shfl_xor(tc, 2); td += __shfl_xor(td, 2);
    ta += __shfl_xor(ta, 1); tb += __shfl_xor(tb, 1); tc += __shfl_xor(tc, 1); td += __shfl_xor(td, 1);

    float pa = __builtin_amdgcn_exp2f(ta);
    float pb = __builtin_amdgcn_exp2f(tb);
    float pc = __builtin_amdgcn_exp2f(tc);
    float pd = __builtin_amdgcn_exp2f(td);
    lsum += (pa + pb) + (pc + pd);
    acc0 += pa * xa0 + pb * xb0 + pc * xc0 + pd * xd0;
    acc1 += pa * xa1 + pb * xb1 + pc * xc1 + pd * xd1;
    acc2 += pa * xa2 + pb * xb2 + pc * xc2 + pd * xd2;
    acc3 += pa * xa3 + pb * xb3 + pc * xc3 + pd * xd3;
  }
  for (; e < e1; e++) {
    int s0 = csr_src[e];
    ushort4v a4 = *(const ushort4v*)&C1[(size_t)s0 * 512 + 4 * lane];
    float xa0 = bf2f(a4[0]), xa1 = bf2f(a4[1]), xa2 = bf2f(a4[2]), xa3 = bf2f(a4[3]);
    float ta;
    EDGE_SCORE(ta, xa0, xa1, xa2, xa3);
    ta += __shfl_xor(ta, 8);
    ta += __shfl_xor(ta, 4);
    ta += __shfl_xor(ta, 2);
    ta += __shfl_xor(ta, 1);
    float pa = __builtin_amdgcn_exp2f(ta);
    lsum += pa;
    acc0 += pa * xa0;
    acc1 += pa * xa1;
    acc2 += pa * xa2;
    acc3 += pa * xa3;
  }
#undef EDGE_SCORE

  float inv = 1.f / (lsum + 1e-16f);
  float4 bv = *(const float4*)&bias[4 * lane];
  float4 o;
  o.x = acc0 * inv + bv.x;
  o.y = acc1 * inv + bv.y;
  o.z = acc2 * inv + bv.z;
  o.w = acc3 * inv + bv.w;
  *(float4*)&out[(size_t)n * 256 + 4 * lane] = o;
}

// ---------------- GATv2 aggregation, layer 2 ----------------
// Wave per node; 4 x 16-lane groups each process a different edge (4 dims/lane).
__global__ void agg2_kernel(const unsigned short* __restrict__ xlr,
                            const float* __restrict__ att, const float* __restrict__ bias,
                            const int* __restrict__ rowptr, const int* __restrict__ csr_src,
                            float* __restrict__ out) {
  int wave = threadIdx.x >> 6;
  int lane = threadIdx.x & 63;
  int n = blockIdx.x * 4 + wave;
  if (n >= N_NODES) return;

  int g = lane >> 4, slot = lane & 15;
  ushort4v xi4 = *(const ushort4v*)&xlr[(size_t)n * 128 + 64 + 4 * slot];
  float xi0 = bf2f(xi4[0]), xi1 = bf2f(xi4[1]), xi2 = bf2f(xi4[2]), xi3 = bf2f(xi4[3]);
  float4 attv = *(const float4*)&att[4 * slot];
  attv.x *= LOG2E; attv.y *= LOG2E; attv.z *= LOG2E; attv.w *= LOG2E;

  float acc0 = 0.f, acc1 = 0.f, acc2 = 0.f, acc3 = 0.f;
  float lsum = 0.f;

  int e0 = rowptr[n], e1 = rowptr[n + 1];
  int nt = (e1 - e0 + 3) >> 2;
  for (int it = 0; it < nt; it++) {
    int e = e0 + it * 4 + g;
    bool valid = e < e1;
    int s = valid ? csr_src[e] : 0;
    ushort4v xj4 = *(const ushort4v*)&xlr[(size_t)s * 128 + 4 * slot];
    float xj0 = bf2f(xj4[0]), xj1 = bf2f(xj4[1]), xj2 = bf2f(xj4[2]), xj3 = bf2f(xj4[3]);
    float u0 = xi0 + xj0, u1 = xi1 + xj1, u2 = xi2 + xj2, u3 = xi3 + xj3;
    float t = fmaxf(u0, NEG_SLOPE * u0) * attv.x + fmaxf(u1, NEG_SLOPE * u1) * attv.y +
              fmaxf(u2, NEG_SLOPE * u2) * attv.z + fmaxf(u3, NEG_SLOPE * u3) * attv.w;
    t += __shfl_xor(t, 8);
    t += __shfl_xor(t, 4);
    t += __shfl_xor(t, 2);
    t += __shfl_xor(t, 1);
    float p = valid ? __builtin_amdgcn_exp2f(t) : 0.f;
    lsum += p;
    acc0 += p * xj0;
    acc1 += p * xj1;
    acc2 += p * xj2;
    acc3 += p * xj3;
  }

  acc0 += __shfl_xor(acc0, 16); acc0 += __shfl_xor(acc0, 32);
  acc1 += __shfl_xor(acc1, 16); acc1 += __shfl_xor(acc1, 32);
  acc2 += __shfl_xor(acc2, 16); acc2 += __shfl_xor(acc2, 32);
  acc3 += __shfl_xor(acc3, 16); acc3 += __shfl_xor(acc3, 32);
  lsum += __shfl_xor(lsum, 16); lsum += __shfl_xor(lsum, 32);

  if (g == 0) {
    float inv = 1.f / (lsum + 1e-16f);
    float4 bv = *(const float4*)&bias[4 * slot];
    float4 o;
    o.x = acc0 * inv + bv.x;
    o.y = acc1 * inv + bv.y;
    o.z = acc2 * inv + bv.z;
    o.w = acc3 * inv + bv.w;
    *(float4*)&out[(size_t)n * 64 + 4 * slot] = o;
  }
}

// ---------------- BN stage 1, C=256 ----------------
__global__ void bn_stage1_256_kernel(const float* __restrict__ x, float* __restrict__ partial) {
  int c = threadIdx.x;
  int r0 = blockIdx.x * 84;
  int r1 = min(r0 + 84, N_NODES);
  float s = 0.f, q = 0.f;
  for (int r = r0; r < r1; r++) {
    float v = x[(size_t)r * 256 + c];
    s += v;
    q += v * v;
  }
  partial[(size_t)blockIdx.x * 512 + c] = s;
  partial[(size_t)blockIdx.x * 512 + 256 + c] = q;
}

// ---------------- BN stage 1, C=64 ----------------
__global__ void bn_stage1_64_kernel(const float* __restrict__ x, float* __restrict__ partial) {
  __shared__ float ls[256], lq[256];
  int tid = threadIdx.x;
  int c = tid & 63, g = tid >> 6;
  int r0 = blockIdx.x * 84 + g;
  int r1 = min(blockIdx.x * 84 + 84, N_NODES);
  float s = 0.f, q = 0.f;
  for (int r = r0; r < r1; r += 4) {
    float v = x[(size_t)r * 64 + c];
    s += v;
    q += v * v;
  }
  ls[tid] = s;
  lq[tid] = q;
  __syncthreads();
  if (g == 0) {
    s += ls[64 + c] + ls[128 + c] + ls[192 + c];
    q += lq[64 + c] + lq[128 + c] + lq[192 + c];
    partial[(size_t)blockIdx.x * 128 + c] = s;
    partial[(size_t)blockIdx.x * 128 + 64 + c] = q;
  }
}

// ---------------- BN stage 2: finalize scale/shift ----------------
__global__ void bn_stage2_kernel(const float* __restrict__ partial, int C,
                                 const float* __restrict__ gamma, const float* __restrict__ beta,
                                 float* __restrict__ ss) {
  int c = threadIdx.x;
  if (c >= C) return;
  float s = 0.f, q = 0.f;
  for (int b = 0; b < 240; b++) {
    s += partial[(size_t)b * 2 * C + c];
    q += partial[(size_t)b * 2 * C + C + c];
  }
  float mu = s * (1.0f / N_NODES);
  float var = q * (1.0f / N_NODES) - mu * mu;
  float sc = gamma[c] * rsqrtf(var + BN_EPS);
  ss[c] = sc;
  ss[C + c] = beta[c] - mu * sc;
}

// ---------------- classifier head: fused BN2+GELU on load, + log_softmax ----------------
__global__ void head_kernel(const float* __restrict__ h, const float* __restrict__ ss2,
                            const float* __restrict__ Wc, const float* __restrict__ bc,
                            float* __restrict__ out) {
  __shared__ float Ws[HID * OUTC];
  __shared__ float bs[OUTC];
  for (int i = threadIdx.x; i < HID * OUTC; i += 256) Ws[i] = Wc[i];
  for (int i = threadIdx.x; i < OUTC; i += 256) bs[i] = bc[i];
  __syncthreads();

  int wave = threadIdx.x >> 6;
  int lane = threadIdx.x & 63;
  int n = blockIdx.x * 4 + wave;
  if (n >= N_NODES) return;

  float raw = h[(size_t)n * HID + lane];
  float hrow = gelu_exact(raw * ss2[lane] + ss2[64 + lane]);
  float dot = 0.f;
#pragma unroll
  for (int k = 0; k < HID; k++) {
    float hk = __shfl(hrow, k);
    if (lane < OUTC) dot += hk * Ws[k * OUTC + lane];
  }
  float z = (lane < OUTC) ? (dot + bs[lane]) : -INFINITY;
  float mv = z;
  for (int off = 32; off; off >>= 1) mv = fmaxf(mv, __shfl_xor(mv, off));
  float p = (lane < OUTC) ? expf(z - mv) : 0.f;
  float sum = p;
  for (int off = 32; off; off >>= 1) sum += __shfl_xor(sum, off);
  if (lane < OUTC) out[(size_t)n * OUTC + lane] = z - mv - logf(sum);
}

// ---------------- launch ----------------
extern "C" void kernel_launch(void* const* d_in, const int* in_sizes, int n_in,
                              void* d_out, int out_size, void* d_ws, size_t ws_size,
                              hipStream_t stream) {
  const float* x = (const float*)d_in[0];
  const int* eidx = (const int*)d_in[1];
  const float* W1l = (const float*)d_in[2];
  const float* W1r = (const float*)d_in[3];
  const float* att1 = (const float*)d_in[4];
  const float* b1 = (const float*)d_in[5];
  const float* bn1_g = (const float*)d_in[6];
  const float* bn1_b = (const float*)d_in[7];
  const float* W2l = (const float*)d_in[8];
  const float* W2r = (const float*)d_in[9];
  const float* att2 = (const float*)d_in[10];
  const float* b2 = (const float*)d_in[11];
  const float* bn2_g = (const float*)d_in[12];
  const float* bn2_b = (const float*)d_in[13];
  const float* Wc = (const float*)d_in[14];
  const float* bc = (const float*)d_in[15];
  float* out = (float*)d_out;

  const int* src = eidx;
  const int* dstv = eidx + N_EDGES;

  char* ws = (char*)d_ws;
  unsigned short* C1full = (unsigned short*)(ws + 0);        // [20000][512] bf16, 20,480,000
  float* out1 = (float*)(ws + 20971520);                     // [20000][256] f32, 20,480,000
  unsigned short* C2full = (unsigned short*)(ws + 52428800); // [20000][128] bf16, 5,120,000
  unsigned short* xb = (unsigned short*)(ws + 62914560);     // [20000][256] bf16, 10,240,000
  float* out2 = (float*)(ws + 62914560);                     // 5,120,000 (after xb dead)
  float* partial = (float*)(ws + 73400320);                  // 240*512 f32 = 491,520
  float* ss1 = (float*)(ws + 73891840);                      // 512 f32
  float* ss2 = (float*)(ws + 73893888);                      // 128 f32
  unsigned short* w1bT = (unsigned short*)(ws + 73894400);   // [512][256] bf16, 262,144
  unsigned short* w2bT = (unsigned short*)(ws + 74156544);   // [128][256] bf16, 65,536
  int* deg = (int*)(ws + 74222080);                          // 80,000
  int* cursor = (int*)(ws + 74302080);                       // 80,000 (contiguous)
  int* rowptr = (int*)(ws + 74382080);                       // 80,016
  int* csr_src = (int*)(ws + 74462096);                      // 1,280,000 -> ends 75,742,096

  hipMemsetAsync(deg, 0, 160000, stream);  // deg + cursor

  // fused casts + weight transpose + degree histogram
  cast_all_kernel<<<5000, 256, 0, stream>>>(x, xb, W1l, W1r, W2l, W2r, w1bT, w2bT, dstv, deg);

  // layer-1 transform (N=512, [xl|xr]) with fused rowptr scan (grid row 157)
  gemm_bf16_kernel<<<dim3(4, 158), 256, 0, stream>>>(xb, w1bT, C1full, N_NODES, 256, 512,
                                                     deg, rowptr);

  // CSR scatter
  scatter_kernel<<<(N_EDGES + 255) / 256, 256, 0, stream>>>(src, dstv, rowptr, cursor, csr_src);

  // layer-1 attention aggregation (+bias) -> out1 (f32)
  agg1_kernel<<<N_NODES / 4, 256, 0, stream>>>(C1full, att1, b1, rowptr, csr_src, out1);

  // BN1 stats (finalize+GELU fused into GEMM2's A staging)
  bn_stage1_256_kernel<<<240, 256, 0, stream>>>(out1, partial);
  bn_stage2_kernel<<<1, 256, 0, stream>>>(partial, 256, bn1_g, bn1_b, ss1);

  // layer-2 transform: fused BN1+GELU+cast + GEMM (N=128, [xl2|xr2])
  gemm2_fused_kernel<<<dim3(1, 157), 256, 0, stream>>>(out1, ss1, w2bT, C2full, N_NODES, 256, 128);

  // layer-2 attention aggregation (+bias)
  agg2_kernel<<<N_NODES / 4, 256, 0, stream>>>(C2full, att2, b2, rowptr, csr_src, out2);

  // BN2 stats (finalize+GELU fused into head)
  bn_stage1_64_kernel<<<240, 256, 0, stream>>>(out2, partial);
  bn_stage2_kernel<<<1, 64, 0, stream>>>(partial, 64, bn2_g, bn2_b, ss2);

  // classifier + log_softmax (BN2+GELU applied on load)
  head_kernel<<<N_NODES / 4, 256, 0, stream>>>(out2, ss2, Wc, bc, out);
}

// Round 11
// 258.698 us; speedup vs baseline: 1.0845x; 1.0194x over previous
//
#include <hip/hip_runtime.h>
#include <math.h>

#define N_NODES 20000
#define N_EDGES 320000
#define NODE_DIM 256
#define HID 64
#define HEADS 4
#define OUTC 50
#define NEG_SLOPE 0.2f
#define BN_EPS 1e-5f
#define LOG2E 1.4426950408889634f

typedef __attribute__((ext_vector_type(8))) short short8;
typedef __attribute__((ext_vector_type(8))) unsigned short ushort8;
typedef __attribute__((ext_vector_type(4))) unsigned short ushort4v;
typedef __attribute__((ext_vector_type(4))) float f32x4;

__device__ inline unsigned short f2bf(float f) {
  unsigned u = __float_as_uint(f);
  u += 0x7fffu + ((u >> 16) & 1u);
  return (unsigned short)(u >> 16);
}

__device__ inline float bf2f(unsigned short u) {
  return __uint_as_float((unsigned)u << 16);
}

__device__ inline float gelu_exact(float v) {
  return 0.5f * v * (1.f + erff(v * 0.70710678118f));
}

// ---------------- fused: x cast, weight transpose-cast, degree histogram ----------------
// w1bT[512][256] = [W1l | W1r]^T, w2bT[128][256] = [W2l | W2r]^T
__global__ void cast_all_kernel(const float* __restrict__ x, unsigned short* __restrict__ xb,
                                const float* __restrict__ W1l, const float* __restrict__ W1r,
                                const float* __restrict__ W2l, const float* __restrict__ W2r,
                                unsigned short* __restrict__ w1bT,
                                unsigned short* __restrict__ w2bT,
                                const int* __restrict__ dst, int* __restrict__ deg) {
  int i = blockIdx.x * blockDim.x + threadIdx.x;
  if (i < 1280000) {
    float4 v = ((const float4*)x)[i];
    ushort4v o = {f2bf(v.x), f2bf(v.y), f2bf(v.z), f2bf(v.w)};
    ((ushort4v*)xb)[i] = o;
  }
  if (i < 131072) {
    int j = i >> 8, k = i & 255;  // j = output col, k = input dim
    w1bT[i] = f2bf(j < 256 ? W1l[k * 256 + j] : W1r[k * 256 + j - 256]);
  }
  if (i < 32768) {
    int j = i >> 8, k = i & 255;
    w2bT[i] = f2bf(j < 64 ? W2l[k * 64 + j] : W2r[k * 64 + j - 64]);
  }
  if (i < N_EDGES) atomicAdd(&deg[dst[i]], 1);
}

// ---------------- exclusive scan of deg -> rowptr (1 block x 1024) ----------------
__global__ void scan_kernel(const int* __restrict__ deg, int* __restrict__ rowptr) {
  __shared__ int part[1024];
  int tid = threadIdx.x;
  const int CH = (N_NODES + 1023) / 1024;  // 20
  int base = tid * CH;
  int s = 0;
#pragma unroll
  for (int i = 0; i < CH; i++) {
    int idx = base + i;
    if (idx < N_NODES) s += deg[idx];
  }
  part[tid] = s;
  __syncthreads();
  for (int off = 1; off < 1024; off <<= 1) {
    int v = (tid >= off) ? part[tid - off] : 0;
    __syncthreads();
    part[tid] += v;
    __syncthreads();
  }
  int run = (tid == 0) ? 0 : part[tid - 1];
#pragma unroll
  for (int i = 0; i < CH; i++) {
    int idx = base + i;
    if (idx < N_NODES) {
      rowptr[idx] = run;
      run += deg[idx];
    }
  }
  if (tid == 1023) rowptr[N_NODES] = run;
}

// ---------------- bf16 MFMA GEMM: C[M,N] = A[M,K] @ BT[N,K]^T, bf16 out ----------------
// BM=128, BN=128, BK=32. 256 threads = 4 waves.
__global__ __launch_bounds__(256) void gemm_bf16_kernel(
    const unsigned short* __restrict__ A, const unsigned short* __restrict__ BT,
    unsigned short* __restrict__ C, int M, int K, int N) {
  __shared__ unsigned short As[128][40];
  __shared__ unsigned short Bs[128][40];
  int tid = threadIdx.x;
  int lane = tid & 63, w = tid >> 6;
  int bm = blockIdx.y * 128, bn = blockIdx.x * 128;

  f32x4 acc[2][8] = {};

  for (int k0 = 0; k0 < K; k0 += 32) {
#pragma unroll
    for (int s = tid; s < 512; s += 256) {
      int row = s >> 2, half = s & 3;
      int gr = bm + row;
      ushort8 v = {0, 0, 0, 0, 0, 0, 0, 0};
      if (gr < M) v = *(const ushort8*)&A[(size_t)gr * K + k0 + half * 8];
      *(ushort8*)&As[row][half * 8] = v;
    }
#pragma unroll
    for (int s = tid; s < 512; s += 256) {
      int row = s >> 2, half = s & 3;
      ushort8 v = *(const ushort8*)&BT[(size_t)(bn + row) * K + k0 + half * 8];
      *(ushort8*)&Bs[row][half * 8] = v;
    }
    __syncthreads();

    short8 av[2], bv[8];
#pragma unroll
    for (int fr = 0; fr < 2; fr++)
      av[fr] = *(const short8*)&As[w * 32 + fr * 16 + (lane & 15)][(lane >> 4) * 8];
#pragma unroll
    for (int fc = 0; fc < 8; fc++)
      bv[fc] = *(const short8*)&Bs[fc * 16 + (lane & 15)][(lane >> 4) * 8];
#pragma unroll
    for (int fr = 0; fr < 2; fr++)
#pragma unroll
      for (int fc = 0; fc < 8; fc++)
        acc[fr][fc] = __builtin_amdgcn_mfma_f32_16x16x32_bf16(av[fr], bv[fc], acc[fr][fc], 0, 0, 0);
    __syncthreads();
  }

#pragma unroll
  for (int fr = 0; fr < 2; fr++)
#pragma unroll
    for (int fc = 0; fc < 8; fc++)
#pragma unroll
      for (int i = 0; i < 4; i++) {
        int r = bm + w * 32 + fr * 16 + (lane >> 4) * 4 + i;
        if (r < M) C[(size_t)r * N + bn + fc * 16 + (lane & 15)] = f2bf(acc[fr][fc][i]);
      }
}

// ---------------- GEMM2 with fused BN1+GELU+cast on the A operand ----------------
__global__ __launch_bounds__(256) void gemm2_fused_kernel(
    const float* __restrict__ A32, const float* __restrict__ ss,
    const unsigned short* __restrict__ BT, unsigned short* __restrict__ C,
    int M, int K, int N) {
  __shared__ unsigned short As[128][40];
  __shared__ unsigned short Bs[128][40];
  __shared__ float ssA[512];
  int tid = threadIdx.x;
  int lane = tid & 63, w = tid >> 6;
  int bm = blockIdx.y * 128, bn = blockIdx.x * 128;

  for (int i = tid; i < 512; i += 256) ssA[i] = ss[i];
  __syncthreads();

  f32x4 acc[2][8] = {};

  for (int k0 = 0; k0 < K; k0 += 32) {
#pragma unroll
    for (int s = tid; s < 512; s += 256) {
      int row = s >> 2, half = s & 3;
      int gr = bm + row;
      int c0 = k0 + half * 8;
      ushort8 o8 = {0, 0, 0, 0, 0, 0, 0, 0};
      if (gr < M) {
        float4 va = *(const float4*)&A32[(size_t)gr * K + c0];
        float4 vb = *(const float4*)&A32[(size_t)gr * K + c0 + 4];
        o8[0] = f2bf(gelu_exact(va.x * ssA[c0 + 0] + ssA[256 + c0 + 0]));
        o8[1] = f2bf(gelu_exact(va.y * ssA[c0 + 1] + ssA[256 + c0 + 1]));
        o8[2] = f2bf(gelu_exact(va.z * ssA[c0 + 2] + ssA[256 + c0 + 2]));
        o8[3] = f2bf(gelu_exact(va.w * ssA[c0 + 3] + ssA[256 + c0 + 3]));
        o8[4] = f2bf(gelu_exact(vb.x * ssA[c0 + 4] + ssA[256 + c0 + 4]));
        o8[5] = f2bf(gelu_exact(vb.y * ssA[c0 + 5] + ssA[256 + c0 + 5]));
        o8[6] = f2bf(gelu_exact(vb.z * ssA[c0 + 6] + ssA[256 + c0 + 6]));
        o8[7] = f2bf(gelu_exact(vb.w * ssA[c0 + 7] + ssA[256 + c0 + 7]));
      }
      *(ushort8*)&As[row][half * 8] = o8;
    }
#pragma unroll
    for (int s = tid; s < 512; s += 256) {
      int row = s >> 2, half = s & 3;
      ushort8 v = *(const ushort8*)&BT[(size_t)(bn + row) * K + k0 + half * 8];
      *(ushort8*)&Bs[row][half * 8] = v;
    }
    __syncthreads();

    short8 av[2], bv[8];
#pragma unroll
    for (int fr = 0; fr < 2; fr++)
      av[fr] = *(const short8*)&As[w * 32 + fr * 16 + (lane & 15)][(lane >> 4) * 8];
#pragma unroll
    for (int fc = 0; fc < 8; fc++)
      bv[fc] = *(const short8*)&Bs[fc * 16 + (lane & 15)][(lane >> 4) * 8];
#pragma unroll
    for (int fr = 0; fr < 2; fr++)
#pragma unroll
      for (int fc = 0; fc < 8; fc++)
        acc[fr][fc] = __builtin_amdgcn_mfma_f32_16x16x32_bf16(av[fr], bv[fc], acc[fr][fc], 0, 0, 0);
    __syncthreads();
  }

#pragma unroll
  for (int fr = 0; fr < 2; fr++)
#pragma unroll
    for (int fc = 0; fc < 8; fc++)
#pragma unroll
      for (int i = 0; i < 4; i++) {
        int r = bm + w * 32 + fr * 16 + (lane >> 4) * 4 + i;
        if (r < M) C[(size_t)r * N + bn + fc * 16 + (lane & 15)] = f2bf(acc[fr][fc][i]);
      }
}

// ---------------- CSR scatter ----------------
__global__ void scatter_kernel(const int* __restrict__ src, const int* __restrict__ dst,
                               const int* __restrict__ rowptr, int* __restrict__ cursor,
                               int* __restrict__ csr_src) {
  int i = blockIdx.x * blockDim.x + threadIdx.x;
  if (i < N_EDGES) {
    int d = dst[i];
    int pos = rowptr[d] + atomicAdd(&cursor[d], 1);
    csr_src[pos] = src[i];
  }
}

// ---------------- GATv2 aggregation, layer 1 ----------------
// Wave per node. Lane l: head h=l>>4, channels 4l..4l+3. 4-step group butterfly.
// att pre-scaled by LOG2E so p = exp2(t). Edge loop unrolled x4.
__global__ void agg1_kernel(const unsigned short* __restrict__ C1,
                            const float* __restrict__ att, const float* __restrict__ bias,
                            const int* __restrict__ rowptr, const int* __restrict__ csr_src,
                            float* __restrict__ out) {
  int wave = threadIdx.x >> 6;
  int lane = threadIdx.x & 63;
  int n = blockIdx.x * 4 + wave;
  if (n >= N_NODES) return;

  ushort4v xi4 = *(const ushort4v*)&C1[(size_t)n * 512 + 256 + 4 * lane];
  float xi0 = bf2f(xi4[0]), xi1 = bf2f(xi4[1]), xi2 = bf2f(xi4[2]), xi3 = bf2f(xi4[3]);
  float4 attv = *(const float4*)&att[4 * lane];
  attv.x *= LOG2E; attv.y *= LOG2E; attv.z *= LOG2E; attv.w *= LOG2E;

  float acc0 = 0.f, acc1 = 0.f, acc2 = 0.f, acc3 = 0.f;
  float lsum = 0.f;

  int e0 = rowptr[n], e1 = rowptr[n + 1];
  int e = e0;
#define EDGE_SCORE(T, X0, X1, X2, X3)                                                 \
  {                                                                                   \
    float u0 = xi0 + X0, u1 = xi1 + X1, u2 = xi2 + X2, u3 = xi3 + X3;                 \
    T = fmaxf(u0, NEG_SLOPE * u0) * attv.x + fmaxf(u1, NEG_SLOPE * u1) * attv.y +     \
        fmaxf(u2, NEG_SLOPE * u2) * attv.z + fmaxf(u3, NEG_SLOPE * u3) * attv.w;      \
  }
  for (; e + 4 <= e1; e += 4) {
    int s0 = csr_src[e], s1 = csr_src[e + 1], s2 = csr_src[e + 2], s3 = csr_src[e + 3];
    ushort4v a4 = *(const ushort4v*)&C1[(size_t)s0 * 512 + 4 * lane];
    ushort4v b4 = *(const ushort4v*)&C1[(size_t)s1 * 512 + 4 * lane];
    ushort4v c4 = *(const ushort4v*)&C1[(size_t)s2 * 512 + 4 * lane];
    ushort4v d4 = *(const ushort4v*)&C1[(size_t)s3 * 512 + 4 * lane];
    float xa0 = bf2f(a4[0]), xa1 = bf2f(a4[1]), xa2 = bf2f(a4[2]), xa3 = bf2f(a4[3]);
    float xb0 = bf2f(b4[0]), xb1 = bf2f(b4[1]), xb2 = bf2f(b4[2]), xb3 = bf2f(b4[3]);
    float xc0 = bf2f(c4[0]), xc1 = bf2f(c4[1]), xc2 = bf2f(c4[2]), xc3 = bf2f(c4[3]);
    float xd0 = bf2f(d4[0]), xd1 = bf2f(d4[1]), xd2 = bf2f(d4[2]), xd3 = bf2f(d4[3]);

    float ta, tb, tc, td;
    EDGE_SCORE(ta, xa0, xa1, xa2, xa3);
    EDGE_SCORE(tb, xb0, xb1, xb2, xb3);
    EDGE_SCORE(tc, xc0, xc1, xc2, xc3);
    EDGE_SCORE(td, xd0, xd1, xd2, xd3);

    ta += __shfl_xor(ta, 8); tb += __shfl_xor(tb, 8); tc += __shfl_xor(tc, 8); td += __shfl_xor(td, 8);
    ta += __shfl_xor(ta, 4); tb += __shfl_xor(tb, 4); tc += __shfl_xor(tc, 4); td += __shfl_xor(td, 4);
    ta += __shfl_xor(ta, 2); tb += __shfl_xor(tb, 2); tc += __shfl_xor(tc, 2); td += __shfl_xor(td, 2);
    ta += __shfl_xor(ta, 1); tb += __shfl_xor(tb, 1); tc += __shfl_xor(tc, 1); td += __shfl_xor(td, 1);

    float pa = __builtin_amdgcn_exp2f(ta);
    float pb = __builtin_amdgcn_exp2f(tb);
    float pc = __builtin_amdgcn_exp2f(tc);
    float pd = __builtin_amdgcn_exp2f(td);
    lsum += (pa + pb) + (pc + pd);
    acc0 += pa * xa0 + pb * xb0 + pc * xc0 + pd * xd0;
    acc1 += pa * xa1 + pb * xb1 + pc * xc1 + pd * xd1;
    acc2 += pa * xa2 + pb * xb2 + pc * xc2 + pd * xd2;
    acc3 += pa * xa3 + pb * xb3 + pc * xc3 + pd * xd3;
  }
  for (; e < e1; e++) {
    int s0 = csr_src[e];
    ushort4v a4 = *(const ushort4v*)&C1[(size_t)s0 * 512 + 4 * lane];
    float xa0 = bf2f(a4[0]), xa1 = bf2f(a4[1]), xa2 = bf2f(a4[2]), xa3 = bf2f(a4[3]);
    float ta;
    EDGE_SCORE(ta, xa0, xa1, xa2, xa3);
    ta += __shfl_xor(ta, 8);
    ta += __shfl_xor(ta, 4);
    ta += __shfl_xor(ta, 2);
    ta += __shfl_xor(ta, 1);
    float pa = __builtin_amdgcn_exp2f(ta);
    lsum += pa;
    acc0 += pa * xa0;
    acc1 += pa * xa1;
    acc2 += pa * xa2;
    acc3 += pa * xa3;
  }
#undef EDGE_SCORE

  float inv = 1.f / (lsum + 1e-16f);
  float4 bv = *(const float4*)&bias[4 * lane];
  float4 o;
  o.x = acc0 * inv + bv.x;
  o.y = acc1 * inv + bv.y;
  o.z = acc2 * inv + bv.z;
  o.w = acc3 * inv + bv.w;
  *(float4*)&out[(size_t)n * 256 + 4 * lane] = o;
}

// ---------------- GATv2 aggregation, layer 2 ----------------
// Wave per node; 4 x 16-lane groups each process a different edge (4 dims/lane).
__global__ void agg2_kernel(const unsigned short* __restrict__ xlr,
                            const float* __restrict__ att, const float* __restrict__ bias,
                            const int* __restrict__ rowptr, const int* __restrict__ csr_src,
                            float* __restrict__ out) {
  int wave = threadIdx.x >> 6;
  int lane = threadIdx.x & 63;
  int n = blockIdx.x * 4 + wave;
  if (n >= N_NODES) return;

  int g = lane >> 4, slot = lane & 15;
  ushort4v xi4 = *(const ushort4v*)&xlr[(size_t)n * 128 + 64 + 4 * slot];
  float xi0 = bf2f(xi4[0]), xi1 = bf2f(xi4[1]), xi2 = bf2f(xi4[2]), xi3 = bf2f(xi4[3]);
  float4 attv = *(const float4*)&att[4 * slot];
  attv.x *= LOG2E; attv.y *= LOG2E; attv.z *= LOG2E; attv.w *= LOG2E;

  float acc0 = 0.f, acc1 = 0.f, acc2 = 0.f, acc3 = 0.f;
  float lsum = 0.f;

  int e0 = rowptr[n], e1 = rowptr[n + 1];
  int nt = (e1 - e0 + 3) >> 2;
  for (int it = 0; it < nt; it++) {
    int e = e0 + it * 4 + g;
    bool valid = e < e1;
    int s = valid ? csr_src[e] : 0;
    ushort4v xj4 = *(const ushort4v*)&xlr[(size_t)s * 128 + 4 * slot];
    float xj0 = bf2f(xj4[0]), xj1 = bf2f(xj4[1]), xj2 = bf2f(xj4[2]), xj3 = bf2f(xj4[3]);
    float u0 = xi0 + xj0, u1 = xi1 + xj1, u2 = xi2 + xj2, u3 = xi3 + xj3;
    float t = fmaxf(u0, NEG_SLOPE * u0) * attv.x + fmaxf(u1, NEG_SLOPE * u1) * attv.y +
              fmaxf(u2, NEG_SLOPE * u2) * attv.z + fmaxf(u3, NEG_SLOPE * u3) * attv.w;
    t += __shfl_xor(t, 8);
    t += __shfl_xor(t, 4);
    t += __shfl_xor(t, 2);
    t += __shfl_xor(t, 1);
    float p = valid ? __builtin_amdgcn_exp2f(t) : 0.f;
    lsum += p;
    acc0 += p * xj0;
    acc1 += p * xj1;
    acc2 += p * xj2;
    acc3 += p * xj3;
  }

  acc0 += __shfl_xor(acc0, 16); acc0 += __shfl_xor(acc0, 32);
  acc1 += __shfl_xor(acc1, 16); acc1 += __shfl_xor(acc1, 32);
  acc2 += __shfl_xor(acc2, 16); acc2 += __shfl_xor(acc2, 32);
  acc3 += __shfl_xor(acc3, 16); acc3 += __shfl_xor(acc3, 32);
  lsum += __shfl_xor(lsum, 16); lsum += __shfl_xor(lsum, 32);

  if (g == 0) {
    float inv = 1.f / (lsum + 1e-16f);
    float4 bv = *(const float4*)&bias[4 * slot];
    float4 o;
    o.x = acc0 * inv + bv.x;
    o.y = acc1 * inv + bv.y;
    o.z = acc2 * inv + bv.z;
    o.w = acc3 * inv + bv.w;
    *(float4*)&out[(size_t)n * 64 + 4 * slot] = o;
  }
}

// ---------------- BN stage 1, C=256 ----------------
__global__ void bn_stage1_256_kernel(const float* __restrict__ x, float* __restrict__ partial) {
  int c = threadIdx.x;
  int r0 = blockIdx.x * 84;
  int r1 = min(r0 + 84, N_NODES);
  float s = 0.f, q = 0.f;
  for (int r = r0; r < r1; r++) {
    float v = x[(size_t)r * 256 + c];
    s += v;
    q += v * v;
  }
  partial[(size_t)blockIdx.x * 512 + c] = s;
  partial[(size_t)blockIdx.x * 512 + 256 + c] = q;
}

// ---------------- BN stage 1, C=64 ----------------
__global__ void bn_stage1_64_kernel(const float* __restrict__ x, float* __restrict__ partial) {
  __shared__ float ls[256], lq[256];
  int tid = threadIdx.x;
  int c = tid & 63, g = tid >> 6;
  int r0 = blockIdx.x * 84 + g;
  int r1 = min(blockIdx.x * 84 + 84, N_NODES);
  float s = 0.f, q = 0.f;
  for (int r = r0; r < r1; r += 4) {
    float v = x[(size_t)r * 64 + c];
    s += v;
    q += v * v;
  }
  ls[tid] = s;
  lq[tid] = q;
  __syncthreads();
  if (g == 0) {
    s += ls[64 + c] + ls[128 + c] + ls[192 + c];
    q += lq[64 + c] + lq[128 + c] + lq[192 + c];
    partial[(size_t)blockIdx.x * 128 + c] = s;
    partial[(size_t)blockIdx.x * 128 + 64 + c] = q;
  }
}

// ---------------- BN stage 2: finalize scale/shift ----------------
__global__ void bn_stage2_kernel(const float* __restrict__ partial, int C,
                                 const float* __restrict__ gamma, const float* __restrict__ beta,
                                 float* __restrict__ ss) {
  int c = threadIdx.x;
  if (c >= C) return;
  float s = 0.f, q = 0.f;
  for (int b = 0; b < 240; b++) {
    s += partial[(size_t)b * 2 * C + c];
    q += partial[(size_t)b * 2 * C + C + c];
  }
  float mu = s * (1.0f / N_NODES);
  float var = q * (1.0f / N_NODES) - mu * mu;
  float sc = gamma[c] * rsqrtf(var + BN_EPS);
  ss[c] = sc;
  ss[C + c] = beta[c] - mu * sc;
}

// ---------------- classifier head: fused BN2+GELU on load, + log_softmax ----------------
__global__ void head_kernel(const float* __restrict__ h, const float* __restrict__ ss2,
                            const float* __restrict__ Wc, const float* __restrict__ bc,
                            float* __restrict__ out) {
  __shared__ float Ws[HID * OUTC];
  __shared__ float bs[OUTC];
  for (int i = threadIdx.x; i < HID * OUTC; i += 256) Ws[i] = Wc[i];
  for (int i = threadIdx.x; i < OUTC; i += 256) bs[i] = bc[i];
  __syncthreads();

  int wave = threadIdx.x >> 6;
  int lane = threadIdx.x & 63;
  int n = blockIdx.x * 4 + wave;
  if (n >= N_NODES) return;

  float raw = h[(size_t)n * HID + lane];
  float hrow = gelu_exact(raw * ss2[lane] + ss2[64 + lane]);
  float dot = 0.f;
#pragma unroll
  for (int k = 0; k < HID; k++) {
    float hk = __shfl(hrow, k);
    if (lane < OUTC) dot += hk * Ws[k * OUTC + lane];
  }
  float z = (lane < OUTC) ? (dot + bs[lane]) : -INFINITY;
  float mv = z;
  for (int off = 32; off; off >>= 1) mv = fmaxf(mv, __shfl_xor(mv, off));
  float p = (lane < OUTC) ? expf(z - mv) : 0.f;
  float sum = p;
  for (int off = 32; off; off >>= 1) sum += __shfl_xor(sum, off);
  if (lane < OUTC) out[(size_t)n * OUTC + lane] = z - mv - logf(sum);
}

// ---------------- launch ----------------
extern "C" void kernel_launch(void* const* d_in, const int* in_sizes, int n_in,
                              void* d_out, int out_size, void* d_ws, size_t ws_size,
                              hipStream_t stream) {
  const float* x = (const float*)d_in[0];
  const int* eidx = (const int*)d_in[1];
  const float* W1l = (const float*)d_in[2];
  const float* W1r = (const float*)d_in[3];
  const float* att1 = (const float*)d_in[4];
  const float* b1 = (const float*)d_in[5];
  const float* bn1_g = (const float*)d_in[6];
  const float* bn1_b = (const float*)d_in[7];
  const float* W2l = (const float*)d_in[8];
  const float* W2r = (const float*)d_in[9];
  const float* att2 = (const float*)d_in[10];
  const float* b2 = (const float*)d_in[11];
  const float* bn2_g = (const float*)d_in[12];
  const float* bn2_b = (const float*)d_in[13];
  const float* Wc = (const float*)d_in[14];
  const float* bc = (const float*)d_in[15];
  float* out = (float*)d_out;

  const int* src = eidx;
  const int* dstv = eidx + N_EDGES;

  char* ws = (char*)d_ws;
  unsigned short* C1full = (unsigned short*)(ws + 0);        // [20000][512] bf16, 20,480,000
  float* out1 = (float*)(ws + 20971520);                     // [20000][256] f32, 20,480,000
  unsigned short* C2full = (unsigned short*)(ws + 52428800); // [20000][128] bf16, 5,120,000
  unsigned short* xb = (unsigned short*)(ws + 62914560);     // [20000][256] bf16, 10,240,000
  float* out2 = (float*)(ws + 62914560);                     // 5,120,000 (after xb dead)
  float* partial = (float*)(ws + 73400320);                  // 240*512 f32 = 491,520
  float* ss1 = (float*)(ws + 73891840);                      // 512 f32
  float* ss2 = (float*)(ws + 73893888);                      // 128 f32
  unsigned short* w1bT = (unsigned short*)(ws + 73894400);   // [512][256] bf16, 262,144
  unsigned short* w2bT = (unsigned short*)(ws + 74156544);   // [128][256] bf16, 65,536
  int* deg = (int*)(ws + 74222080);                          // 80,000
  int* cursor = (int*)(ws + 74302080);                       // 80,000 (contiguous)
  int* rowptr = (int*)(ws + 74382080);                       // 80,016
  int* csr_src = (int*)(ws + 74462096);                      // 1,280,000 -> ends 75,742,096

  hipMemsetAsync(deg, 0, 160000, stream);  // deg + cursor

  // fused casts + weight transpose + degree histogram
  cast_all_kernel<<<5000, 256, 0, stream>>>(x, xb, W1l, W1r, W2l, W2r, w1bT, w2bT, dstv, deg);

  // rowptr scan (1 small block; kept separate — fusing it into the GEMM pinned
  // the whole GEMM dispatch to the serial scan block's runtime in round 10)
  scan_kernel<<<1, 1024, 0, stream>>>(deg, rowptr);

  // layer-1 transform (N=512, [xl|xr])
  gemm_bf16_kernel<<<dim3(4, 157), 256, 0, stream>>>(xb, w1bT, C1full, N_NODES, 256, 512);

  // CSR scatter
  scatter_kernel<<<(N_EDGES + 255) / 256, 256, 0, stream>>>(src, dstv, rowptr, cursor, csr_src);

  // layer-1 attention aggregation (+bias) -> out1 (f32)
  agg1_kernel<<<N_NODES / 4, 256, 0, stream>>>(C1full, att1, b1, rowptr, csr_src, out1);

  // BN1 stats (finalize+GELU fused into GEMM2's A staging)
  bn_stage1_256_kernel<<<240, 256, 0, stream>>>(out1, partial);
  bn_stage2_kernel<<<1, 256, 0, stream>>>(partial, 256, bn1_g, bn1_b, ss1);

  // layer-2 transform: fused BN1+GELU+cast + GEMM (N=128, [xl2|xr2])
  gemm2_fused_kernel<<<dim3(1, 157), 256, 0, stream>>>(out1, ss1, w2bT, C2full, N_NODES, 256, 128);

  // layer-2 attention aggregation (+bias)
  agg2_kernel<<<N_NODES / 4, 256, 0, stream>>>(C2full, att2, b2, rowptr, csr_src, out2);

  // BN2 stats (finalize+GELU fused into head)
  bn_stage1_64_kernel<<<240, 256, 0, stream>>>(out2, partial);
  bn_stage2_kernel<<<1, 64, 0, stream>>>(partial, 64, bn2_g, bn2_b, ss2);

  // classifier + log_softmax (BN2+GELU applied on load)
  head_kernel<<<N_NODES / 4, 256, 0, stream>>>(out2, ss2, Wc, bc, out);
}